// Round 2
// baseline (4959.185 us; speedup 1.0000x reference)
//
#include <hip/hip_runtime.h>
#include <math.h>

// UrbanModelV2: encoder MLPs -> 4x GCNConv (2 graphs) -> gated combine -> LN-MLP head.
// N=100000, CTX=128, TGT=32, H=64, FUS=96, E1=1.6M, E2=0.8M. All fp32.
//
// R2: added runtime dtype detection for `mask` (uint8 vs int32 bool storage) and
// edge indices (int32 vs int64) — R1's uint8 assumption for mask is the prime
// suspect for the O(1) absmax failure.
//
// ws layout (floats):
//   flags   [2]  (int: flags[0]=mask-is-uint8, flags[1]=ei-is-int32)
//   fused   [N*96]
//   dinv_a  [N], dinv_t [N]
//   lin     [N*64]   (x@W scratch)
//   agg     [N*64]   (scatter accumulator)
//   h1      [N*64]
//   hacc    [N*64]

#define LN_EPS 1e-5f

__device__ __forceinline__ float gelu_exact(float x) {
    return 0.5f * x * (1.0f + erff(x * 0.70710678118654752440f));
}

__device__ __forceinline__ float wave_sum64(float v) {
#pragma unroll
    for (int off = 32; off > 0; off >>= 1)
        v += __shfl_xor(v, off, 64);
    return v;
}

__device__ __forceinline__ int load_edge(const void* ei, int is32, long idx) {
    return is32 ? ((const int*)ei)[idx] : (int)((const long long*)ei)[idx];
}

// ---------------- dtype detection ----------------
__global__ void detect_kernel(const unsigned char* __restrict__ mask_bytes,
                              const int* __restrict__ ei_words,
                              int* __restrict__ flags) {
    if (threadIdx.x == 0 && blockIdx.x == 0) {
        // mask: int32 bool storage => bytes at pos%4!=0 are always 0.
        int any_odd_byte = 0;
        for (int i = 0; i < 256; ++i)
            if ((i & 3) != 0 && mask_bytes[i] != 0) any_odd_byte = 1;
        flags[0] = any_odd_byte;  // 1 => uint8 layout, 0 => int32 layout
        // edge index: int64 storage (values < 2^31) => odd int32 words all 0.
        int any_odd_word = 0;
        for (int i = 1; i < 128; i += 2)
            if (ei_words[i] != 0) any_odd_word = 1;
        flags[1] = any_odd_word;  // 1 => int32 layout, 0 => int64 layout
    }
}

// ---------------- degree / dinv ----------------
__global__ __launch_bounds__(256) void deg_kernel(const void* __restrict__ ei, int e,
                                                  const int* __restrict__ flags,
                                                  float* __restrict__ deg) {
    int i = blockIdx.x * 256 + threadIdx.x;
    if (i >= e) return;
    int d = load_edge(ei, flags[1], (long)e + i);  // dst row
    atomicAdd(&deg[d], 1.0f);
}

__global__ __launch_bounds__(256) void dinv_kernel(float* __restrict__ d, int n2) {
    int i = blockIdx.x * 256 + threadIdx.x;
    if (i < n2) d[i] = rsqrtf(d[i] + 1.0f);  // +1 self-loop
}

// ---------------- encoder -> fused [N,96] ----------------
__global__ __launch_bounds__(256) void encoder_kernel(
    const float* __restrict__ context, const float* __restrict__ target,
    const void* __restrict__ mask, const int* __restrict__ flags,
    const float* __restrict__ mask_token,
    const float* __restrict__ ce_W1, const float* __restrict__ ce_b1,
    const float* __restrict__ ce_g, const float* __restrict__ ce_beta,
    const float* __restrict__ ce_W2, const float* __restrict__ ce_b2,
    const float* __restrict__ te_W, const float* __restrict__ te_b,
    float* __restrict__ fused, int n)
{
    __shared__ float cbuf[4][64];
    __shared__ float tbuf[4][32];
    int w = threadIdx.x >> 6;
    int j = threadIdx.x & 63;
    int row = __builtin_amdgcn_readfirstlane(blockIdx.x * 4 + w);
    if (row >= n) return;  // N % 4 == 0: whole blocks exit uniformly

    const float* xr = context + (long)row * 128;
    float y1 = ce_b1[j];
#pragma unroll
    for (int k = 0; k < 128; ++k)
        y1 = fmaf(xr[k], ce_W1[k * 64 + j], y1);

    float mean = wave_sum64(y1) * (1.0f / 64.0f);
    float xc = y1 - mean;
    float var = wave_sum64(xc * xc) * (1.0f / 64.0f);
    float cval = gelu_exact(xc * rsqrtf(var + LN_EPS) * ce_g[j] + ce_beta[j]);
    cbuf[w][j] = cval;

    if (j < 32) {
        long mi = (long)row * 32 + j;
        int mraw = flags[0] ? (int)((const unsigned char*)mask)[mi]
                            : ((const int*)mask)[mi];
        float m = mraw ? 1.0f : 0.0f;
        tbuf[w][j] = target[mi] * (1.0f - m) + mask_token[j] * m;
    }
    __syncthreads();

    float y2 = ce_b2[j];
#pragma unroll
    for (int k = 0; k < 64; ++k)
        y2 = fmaf(cbuf[w][k], ce_W2[k * 64 + j], y2);
    fused[(long)row * 96 + j] = gelu_exact(y2);

    if (j < 32) {
        float y3 = te_b[j];
#pragma unroll
        for (int k = 0; k < 32; ++k)
            y3 = fmaf(tbuf[w][k], te_W[k * 32 + j], y3);
        fused[(long)row * 96 + 64 + j] = gelu_exact(y3);
    }
}

// ---------------- dense row-wise matmul: y[N,64] = x[N,FIN] @ W[FIN,64] ----------------
template <int FIN>
__global__ __launch_bounds__(256) void matmul_kernel(const float* __restrict__ x,
                                                     const float* __restrict__ W,
                                                     float* __restrict__ y, int n) {
    int w = threadIdx.x >> 6;
    int j = threadIdx.x & 63;
    int row = __builtin_amdgcn_readfirstlane(blockIdx.x * 4 + w);
    if (row >= n) return;
    const float* xr = x + (long)row * FIN;
    float acc = 0.0f;
#pragma unroll
    for (int k = 0; k < FIN; ++k)
        acc = fmaf(xr[k], W[k * 64 + j], acc);
    y[(long)row * 64 + j] = acc;
}

// ---------------- edge scatter: agg[dst] += h[src]*dinv[src]*dinv[dst] ----------------
__global__ __launch_bounds__(256) void scatter_kernel(
    const void* __restrict__ ei, int e, const int* __restrict__ flags,
    const float* __restrict__ dinv, const float* __restrict__ h,
    float* __restrict__ agg)
{
    long idx = (long)blockIdx.x * 256 + threadIdx.x;
    int eidx = (int)(idx >> 4);
    int c = (int)(idx & 15);
    if (eidx >= e) return;
    int is32 = flags[1];
    int s = load_edge(ei, is32, eidx);
    int d = load_edge(ei, is32, (long)e + eidx);
    float norm = dinv[s] * dinv[d];
    const float4 v = *(const float4*)(h + (long)s * 64 + c * 4);
    float* o = agg + (long)d * 64 + c * 4;
    atomicAdd(o + 0, v.x * norm);
    atomicAdd(o + 1, v.y * norm);
    atomicAdd(o + 2, v.z * norm);
    atomicAdd(o + 3, v.w * norm);
}

// ---------------- conv finalize: out = gelu(agg + lin*dinv^2 + b) ----------------
__global__ __launch_bounds__(256) void finalize_gelu_kernel(
    const float* __restrict__ lin, const float* __restrict__ agg,
    const float* __restrict__ dinv, const float* __restrict__ b,
    float* __restrict__ out, int n)
{
    long i = (long)blockIdx.x * 256 + threadIdx.x;
    if (i >= (long)n * 64) return;
    int node = (int)(i >> 6);
    int j = (int)(i & 63);
    float di = dinv[node];
    out[i] = gelu_exact(agg[i] + lin[i] * di * di + b[j]);
}

// ---------------- conv finalize with gating scale; optionally accumulate ----------------
__global__ __launch_bounds__(256) void finalize_scale_kernel(
    const float* __restrict__ lin, const float* __restrict__ agg,
    const float* __restrict__ dinv, const float* __restrict__ b,
    const float* __restrict__ alpha_ptr, int take_one_minus, int accumulate,
    float* __restrict__ out, int n)
{
    long i = (long)blockIdx.x * 256 + threadIdx.x;
    if (i >= (long)n * 64) return;
    int node = (int)(i >> 6);
    int j = (int)(i & 63);
    float a = 1.0f / (1.0f + expf(-alpha_ptr[0]));
    float scale = take_one_minus ? (1.0f - a) : a;
    float di = dinv[node];
    float v = (agg[i] + lin[i] * di * di + b[j]) * scale;
    out[i] = accumulate ? (out[i] + v) : v;
}

// ---------------- head ----------------
__global__ __launch_bounds__(256) void head_kernel(
    const float* __restrict__ hacc, const float* __restrict__ fused,
    const float* __restrict__ h_W1, const float* __restrict__ h_b1,
    const float* __restrict__ h_g, const float* __restrict__ h_beta,
    const float* __restrict__ h_W2, const float* __restrict__ h_b2,
    float* __restrict__ out, int n)
{
    __shared__ float zbuf[4][160];
    __shared__ float z2[4][64];
    int w = threadIdx.x >> 6;
    int j = threadIdx.x & 63;
    int row = __builtin_amdgcn_readfirstlane(blockIdx.x * 4 + w);
    if (row >= n) return;

    zbuf[w][j] = hacc[(long)row * 64 + j];
    zbuf[w][64 + j] = fused[(long)row * 96 + j];
    if (j < 32) zbuf[w][128 + j] = fused[(long)row * 96 + 64 + j];
    __syncthreads();

    float y = h_b1[j];
#pragma unroll
    for (int k = 0; k < 160; ++k)
        y = fmaf(zbuf[w][k], h_W1[k * 64 + j], y);

    float mean = wave_sum64(y) * (1.0f / 64.0f);
    float xc = y - mean;
    float var = wave_sum64(xc * xc) * (1.0f / 64.0f);
    float zv = gelu_exact(xc * rsqrtf(var + LN_EPS) * h_g[j] + h_beta[j]);
    z2[w][j] = zv;
    __syncthreads();

    if (j < 32) {
        float o = h_b2[j];
#pragma unroll
        for (int k = 0; k < 64; ++k)
            o = fmaf(z2[w][k], h_W2[k * 32 + j], o);
        out[(long)row * 32 + j] = o;
    }
}

extern "C" void kernel_launch(void* const* d_in, const int* in_sizes, int n_in,
                              void* d_out, int out_size, void* d_ws, size_t ws_size,
                              hipStream_t stream) {
    const float* context    = (const float*)d_in[0];
    const float* target     = (const float*)d_in[1];
    const void*  mask       = d_in[2];   // bool: uint8 or int32 — detected at runtime
    const void*  adj_ei     = d_in[3];   // int32 or int64 — detected at runtime
    const void*  tr_ei      = d_in[4];
    const float* mask_token = (const float*)d_in[5];
    const float* ce_W1 = (const float*)d_in[6];
    const float* ce_b1 = (const float*)d_in[7];
    const float* ce_g  = (const float*)d_in[8];
    const float* ce_be = (const float*)d_in[9];
    const float* ce_W2 = (const float*)d_in[10];
    const float* ce_b2 = (const float*)d_in[11];
    const float* te_W  = (const float*)d_in[12];
    const float* te_b  = (const float*)d_in[13];
    const float* g1_W  = (const float*)d_in[14];
    const float* g1_b  = (const float*)d_in[15];
    const float* g2_W  = (const float*)d_in[16];
    const float* g2_b  = (const float*)d_in[17];
    const float* t1_W  = (const float*)d_in[18];
    const float* t1_b  = (const float*)d_in[19];
    const float* t2_W  = (const float*)d_in[20];
    const float* t2_b  = (const float*)d_in[21];
    const float* alpha = (const float*)d_in[22];
    const float* h_W1  = (const float*)d_in[23];
    const float* h_b1  = (const float*)d_in[24];
    const float* h_g   = (const float*)d_in[25];
    const float* h_be  = (const float*)d_in[26];
    const float* h_W2  = (const float*)d_in[27];
    const float* h_b2  = (const float*)d_in[28];

    const int N  = in_sizes[0] / 128;
    const int E1 = in_sizes[3] / 2;
    const int E2 = in_sizes[4] / 2;

    int*   flags   = (int*)d_ws;                    // 2 ints (pad to 16 floats)
    float* ws      = (float*)d_ws + 16;
    float* fused   = ws;                            // N*96
    float* dinv_a  = fused + (size_t)N * 96;        // N
    float* dinv_t  = dinv_a + N;                    // N
    float* lin     = dinv_t + N;                    // N*64
    float* agg     = lin + (size_t)N * 64;          // N*64
    float* h1      = agg + (size_t)N * 64;          // N*64
    float* hacc    = h1 + (size_t)N * 64;           // N*64
    float* out     = (float*)d_out;

    const unsigned rowBlocks  = (unsigned)((N + 3) / 4);
    const unsigned elemBlocks = (unsigned)(((size_t)N * 64 + 255) / 256);
    const unsigned e1Blocks   = (unsigned)(((size_t)E1 * 16 + 255) / 256);
    const unsigned e2Blocks   = (unsigned)(((size_t)E2 * 16 + 255) / 256);
    const size_t aggBytes = (size_t)N * 64 * sizeof(float);

    detect_kernel<<<1, 64, 0, stream>>>((const unsigned char*)mask, (const int*)adj_ei, flags);

    // degrees -> dinv
    hipMemsetAsync(dinv_a, 0, (size_t)2 * N * sizeof(float), stream);
    deg_kernel<<<(E1 + 255) / 256, 256, 0, stream>>>(adj_ei, E1, flags, dinv_a);
    deg_kernel<<<(E2 + 255) / 256, 256, 0, stream>>>(tr_ei, E2, flags, dinv_t);
    dinv_kernel<<<(2 * N + 255) / 256, 256, 0, stream>>>(dinv_a, 2 * N);

    // encoders -> fused
    encoder_kernel<<<rowBlocks, 256, 0, stream>>>(context, target, mask, flags, mask_token,
                                                  ce_W1, ce_b1, ce_g, ce_be, ce_W2, ce_b2,
                                                  te_W, te_b, fused, N);

    // ---- spatial branch (adj graph) ----
    matmul_kernel<96><<<rowBlocks, 256, 0, stream>>>(fused, g1_W, lin, N);
    hipMemsetAsync(agg, 0, aggBytes, stream);
    scatter_kernel<<<e1Blocks, 256, 0, stream>>>(adj_ei, E1, flags, dinv_a, lin, agg);
    finalize_gelu_kernel<<<elemBlocks, 256, 0, stream>>>(lin, agg, dinv_a, g1_b, h1, N);

    matmul_kernel<64><<<rowBlocks, 256, 0, stream>>>(h1, g2_W, lin, N);
    hipMemsetAsync(agg, 0, aggBytes, stream);
    scatter_kernel<<<e1Blocks, 256, 0, stream>>>(adj_ei, E1, flags, dinv_a, lin, agg);
    finalize_scale_kernel<<<elemBlocks, 256, 0, stream>>>(lin, agg, dinv_a, g2_b, alpha,
                                                          0, 0, hacc, N);

    // ---- transit branch ----
    matmul_kernel<96><<<rowBlocks, 256, 0, stream>>>(fused, t1_W, lin, N);
    hipMemsetAsync(agg, 0, aggBytes, stream);
    scatter_kernel<<<e2Blocks, 256, 0, stream>>>(tr_ei, E2, flags, dinv_t, lin, agg);
    finalize_gelu_kernel<<<elemBlocks, 256, 0, stream>>>(lin, agg, dinv_t, t1_b, h1, N);

    matmul_kernel<64><<<rowBlocks, 256, 0, stream>>>(h1, t2_W, lin, N);
    hipMemsetAsync(agg, 0, aggBytes, stream);
    scatter_kernel<<<e2Blocks, 256, 0, stream>>>(tr_ei, E2, flags, dinv_t, lin, agg);
    finalize_scale_kernel<<<elemBlocks, 256, 0, stream>>>(lin, agg, dinv_t, t2_b, alpha,
                                                          1, 1, hacc, N);

    // ---- head ----
    head_kernel<<<rowBlocks, 256, 0, stream>>>(hacc, fused, h_W1, h_b1, h_g, h_be,
                                               h_W2, h_b2, out, N);
}

// Round 3
// 1372.855 us; speedup vs baseline: 3.6123x; 3.6123x over previous
//
#include <hip/hip_runtime.h>
#include <math.h>

// UrbanModelV2: encoder MLPs -> 4x GCNConv (2 graphs) -> gated combine -> LN-MLP head.
// N=100000, CTX=128, TGT=32, H=64, FUS=96, E1=1.6M, E2=0.8M. All fp32.
//
// R3: replace atomic push-scatter (78 G atomics/s bound, 80% of runtime) with
// CSR pull-gather. Per launch: build CSR per graph (deg count -> scan -> bucket
// fill of {src, dinv[src]} records), then wave-per-node gather with fused
// finalize (self-loop + bias + gelu / gated accumulate). agg buffer + memsets
// + finalize passes eliminated.

#define LN_EPS 1e-5f

__device__ __forceinline__ float gelu_exact(float x) {
    return 0.5f * x * (1.0f + erff(x * 0.70710678118654752440f));
}

__device__ __forceinline__ float wave_sum64(float v) {
#pragma unroll
    for (int off = 32; off > 0; off >>= 1)
        v += __shfl_xor(v, off, 64);
    return v;
}

__device__ __forceinline__ int load_edge(const void* ei, int is32, long idx) {
    return is32 ? ((const int*)ei)[idx] : (int)((const long long*)ei)[idx];
}

// ---------------- dtype detection ----------------
__global__ void detect_kernel(const unsigned char* __restrict__ mask_bytes,
                              const int* __restrict__ ei_words,
                              int* __restrict__ flags) {
    if (threadIdx.x == 0 && blockIdx.x == 0) {
        int any_odd_byte = 0;
        for (int i = 0; i < 256; ++i)
            if ((i & 3) != 0 && mask_bytes[i] != 0) any_odd_byte = 1;
        flags[0] = any_odd_byte;  // 1 => mask is uint8, 0 => int32
        int any_odd_word = 0;
        for (int i = 1; i < 128; i += 2)
            if (ei_words[i] != 0) any_odd_word = 1;
        flags[1] = any_odd_word;  // 1 => edges int32, 0 => int64
    }
}

// ---------------- CSR build ----------------
__global__ __launch_bounds__(256) void degcount_kernel(const void* __restrict__ ei, int e,
                                                       const int* __restrict__ flags,
                                                       int* __restrict__ deg) {
    int i = blockIdx.x * 256 + threadIdx.x;
    if (i >= e) return;
    int d = load_edge(ei, flags[1], (long)e + i);
    atomicAdd(&deg[d], 1);
}

__global__ __launch_bounds__(256) void dinv_kernel(const int* __restrict__ deg,
                                                   float* __restrict__ dinv, int n) {
    int i = blockIdx.x * 256 + threadIdx.x;
    if (i < n) dinv[i] = rsqrtf((float)deg[i] + 1.0f);  // +1 self-loop
}

// block sums of deg
__global__ __launch_bounds__(256) void scan1_kernel(const int* __restrict__ deg, int n,
                                                    int* __restrict__ bsum) {
    __shared__ int red[4];
    int i = blockIdx.x * 256 + threadIdx.x;
    int v = (i < n) ? deg[i] : 0;
#pragma unroll
    for (int off = 32; off > 0; off >>= 1)
        v += __shfl_xor(v, off, 64);
    if ((threadIdx.x & 63) == 0) red[threadIdx.x >> 6] = v;
    __syncthreads();
    if (threadIdx.x == 0) bsum[blockIdx.x] = red[0] + red[1] + red[2] + red[3];
}

// exclusive scan of block sums (nb <= 512), in place
__global__ __launch_bounds__(512) void scan2_kernel(int* __restrict__ bsum, int nb) {
    __shared__ int s[512];
    int t = threadIdx.x;
    s[t] = (t < nb) ? bsum[t] : 0;
    __syncthreads();
    for (int off = 1; off < 512; off <<= 1) {
        int v = (t >= off) ? s[t - off] : 0;
        __syncthreads();
        if (t >= off) s[t] += v;
        __syncthreads();
    }
    if (t < nb) bsum[t] = (t == 0) ? 0 : s[t - 1];
}

// per-block exclusive scan + block offset -> rowptr & cursor
__global__ __launch_bounds__(256) void scan3_kernel(const int* __restrict__ deg, int n,
                                                    const int* __restrict__ boff,
                                                    int* __restrict__ rowptr,
                                                    int* __restrict__ cursor) {
    __shared__ int s[256];
    int t = threadIdx.x;
    int i = blockIdx.x * 256 + t;
    int v = (i < n) ? deg[i] : 0;
    s[t] = v;
    __syncthreads();
    for (int off = 1; off < 256; off <<= 1) {
        int u = (t >= off) ? s[t - off] : 0;
        __syncthreads();
        if (t >= off) s[t] += u;
        __syncthreads();
    }
    int base = boff[blockIdx.x];
    if (i < n) {
        int excl = base + s[t] - v;
        rowptr[i] = excl;
        cursor[i] = excl;
        if (i == n - 1) rowptr[n] = base + s[t];
    }
}

// bucket fill: edges_out[pos] = {src, dinv[src]}
__global__ __launch_bounds__(256) void fill_kernel(const void* __restrict__ ei, int e,
                                                   const int* __restrict__ flags,
                                                   const float* __restrict__ dinv,
                                                   int* __restrict__ cursor,
                                                   int2* __restrict__ edges) {
    int i = blockIdx.x * 256 + threadIdx.x;
    if (i >= e) return;
    int is32 = flags[1];
    int s = load_edge(ei, is32, i);
    int d = load_edge(ei, is32, (long)e + i);
    int pos = atomicAdd(&cursor[d], 1);
    edges[pos] = make_int2(s, __float_as_int(dinv[s]));
}

// ---------------- encoder -> fused [N,96] ----------------
__global__ __launch_bounds__(256) void encoder_kernel(
    const float* __restrict__ context, const float* __restrict__ target,
    const void* __restrict__ mask, const int* __restrict__ flags,
    const float* __restrict__ mask_token,
    const float* __restrict__ ce_W1, const float* __restrict__ ce_b1,
    const float* __restrict__ ce_g, const float* __restrict__ ce_beta,
    const float* __restrict__ ce_W2, const float* __restrict__ ce_b2,
    const float* __restrict__ te_W, const float* __restrict__ te_b,
    float* __restrict__ fused, int n)
{
    __shared__ float cbuf[4][64];
    __shared__ float tbuf[4][32];
    int w = threadIdx.x >> 6;
    int j = threadIdx.x & 63;
    int row = __builtin_amdgcn_readfirstlane(blockIdx.x * 4 + w);
    if (row >= n) return;

    const float* xr = context + (long)row * 128;
    float y1 = ce_b1[j];
#pragma unroll
    for (int k = 0; k < 128; ++k)
        y1 = fmaf(xr[k], ce_W1[k * 64 + j], y1);

    float mean = wave_sum64(y1) * (1.0f / 64.0f);
    float xc = y1 - mean;
    float var = wave_sum64(xc * xc) * (1.0f / 64.0f);
    float cval = gelu_exact(xc * rsqrtf(var + LN_EPS) * ce_g[j] + ce_beta[j]);
    cbuf[w][j] = cval;

    if (j < 32) {
        long mi = (long)row * 32 + j;
        int mraw = flags[0] ? (int)((const unsigned char*)mask)[mi]
                            : ((const int*)mask)[mi];
        float m = mraw ? 1.0f : 0.0f;
        tbuf[w][j] = target[mi] * (1.0f - m) + mask_token[j] * m;
    }
    __syncthreads();

    float y2 = ce_b2[j];
#pragma unroll
    for (int k = 0; k < 64; ++k)
        y2 = fmaf(cbuf[w][k], ce_W2[k * 64 + j], y2);
    fused[(long)row * 96 + j] = gelu_exact(y2);

    if (j < 32) {
        float y3 = te_b[j];
#pragma unroll
        for (int k = 0; k < 32; ++k)
            y3 = fmaf(tbuf[w][k], te_W[k * 32 + j], y3);
        fused[(long)row * 96 + 64 + j] = gelu_exact(y3);
    }
}

// ---------------- dense row-wise matmul: y[N,64] = x[N,FIN] @ W[FIN,64] ----------------
template <int FIN>
__global__ __launch_bounds__(256) void matmul_kernel(const float* __restrict__ x,
                                                     const float* __restrict__ W,
                                                     float* __restrict__ y, int n) {
    int w = threadIdx.x >> 6;
    int j = threadIdx.x & 63;
    int row = __builtin_amdgcn_readfirstlane(blockIdx.x * 4 + w);
    if (row >= n) return;
    const float* xr = x + (long)row * FIN;
    float acc = 0.0f;
#pragma unroll
    for (int k = 0; k < FIN; ++k)
        acc = fmaf(xr[k], W[k * 64 + j], acc);
    y[(long)row * 64 + j] = acc;
}

// ---------------- gather + fused finalize ----------------
// pre = dinv_d * (sum_{edges} lin[src]*dinv_s  +  dinv_d*lin[node]) + b
// mode 0: out = gelu(pre)
// mode 1: out = a * pre          (a = sigmoid(alpha))
// mode 2: out += (1-a) * pre
__global__ __launch_bounds__(256) void gather_kernel(
    const int* __restrict__ rowptr, const int2* __restrict__ edges,
    const float* __restrict__ dinv, const float* __restrict__ lin,
    const float* __restrict__ b, const float* __restrict__ alpha_ptr, int mode,
    float* __restrict__ out, int n)
{
    int w = threadIdx.x >> 6;
    int j = threadIdx.x & 63;
    int node = __builtin_amdgcn_readfirstlane(blockIdx.x * 4 + w);
    if (node >= n) return;

    int beg = rowptr[node];
    int end = rowptr[node + 1];
    float acc = 0.0f;
    for (int base = beg; base < end; base += 64) {
        int cnt = end - base;
        if (cnt > 64) cnt = 64;
        int2 rec = (j < cnt) ? edges[base + j] : make_int2(0, 0);
        int sj = rec.x;
        float dsj = __int_as_float(rec.y);
        for (int t = 0; t < cnt; ++t) {
            int s = __shfl(sj, t, 64);
            float ds = __shfl(dsj, t, 64);
            acc = fmaf(lin[(long)s * 64 + j], ds, acc);
        }
    }
    float dd = dinv[node];
    float pre = dd * (acc + dd * lin[(long)node * 64 + j]) + b[j];

    long oi = (long)node * 64 + j;
    if (mode == 0) {
        out[oi] = gelu_exact(pre);
    } else {
        float a = 1.0f / (1.0f + expf(-alpha_ptr[0]));
        if (mode == 1) out[oi] = a * pre;
        else           out[oi] += (1.0f - a) * pre;
    }
}

// ---------------- head ----------------
__global__ __launch_bounds__(256) void head_kernel(
    const float* __restrict__ hacc, const float* __restrict__ fused,
    const float* __restrict__ h_W1, const float* __restrict__ h_b1,
    const float* __restrict__ h_g, const float* __restrict__ h_beta,
    const float* __restrict__ h_W2, const float* __restrict__ h_b2,
    float* __restrict__ out, int n)
{
    __shared__ float zbuf[4][160];
    __shared__ float z2[4][64];
    int w = threadIdx.x >> 6;
    int j = threadIdx.x & 63;
    int row = __builtin_amdgcn_readfirstlane(blockIdx.x * 4 + w);
    if (row >= n) return;

    zbuf[w][j] = hacc[(long)row * 64 + j];
    zbuf[w][64 + j] = fused[(long)row * 96 + j];
    if (j < 32) zbuf[w][128 + j] = fused[(long)row * 96 + 64 + j];
    __syncthreads();

    float y = h_b1[j];
#pragma unroll
    for (int k = 0; k < 160; ++k)
        y = fmaf(zbuf[w][k], h_W1[k * 64 + j], y);

    float mean = wave_sum64(y) * (1.0f / 64.0f);
    float xc = y - mean;
    float var = wave_sum64(xc * xc) * (1.0f / 64.0f);
    float zv = gelu_exact(xc * rsqrtf(var + LN_EPS) * h_g[j] + h_beta[j]);
    z2[w][j] = zv;
    __syncthreads();

    if (j < 32) {
        float o = h_b2[j];
#pragma unroll
        for (int k = 0; k < 64; ++k)
            o = fmaf(z2[w][k], h_W2[k * 32 + j], o);
        out[(long)row * 32 + j] = o;
    }
}

extern "C" void kernel_launch(void* const* d_in, const int* in_sizes, int n_in,
                              void* d_out, int out_size, void* d_ws, size_t ws_size,
                              hipStream_t stream) {
    const float* context    = (const float*)d_in[0];
    const float* target     = (const float*)d_in[1];
    const void*  mask       = d_in[2];
    const void*  adj_ei     = d_in[3];
    const void*  tr_ei      = d_in[4];
    const float* mask_token = (const float*)d_in[5];
    const float* ce_W1 = (const float*)d_in[6];
    const float* ce_b1 = (const float*)d_in[7];
    const float* ce_g  = (const float*)d_in[8];
    const float* ce_be = (const float*)d_in[9];
    const float* ce_W2 = (const float*)d_in[10];
    const float* ce_b2 = (const float*)d_in[11];
    const float* te_W  = (const float*)d_in[12];
    const float* te_b  = (const float*)d_in[13];
    const float* g1_W  = (const float*)d_in[14];
    const float* g1_b  = (const float*)d_in[15];
    const float* g2_W  = (const float*)d_in[16];
    const float* g2_b  = (const float*)d_in[17];
    const float* t1_W  = (const float*)d_in[18];
    const float* t1_b  = (const float*)d_in[19];
    const float* t2_W  = (const float*)d_in[20];
    const float* t2_b  = (const float*)d_in[21];
    const float* alpha = (const float*)d_in[22];
    const float* h_W1  = (const float*)d_in[23];
    const float* h_b1  = (const float*)d_in[24];
    const float* h_g   = (const float*)d_in[25];
    const float* h_be  = (const float*)d_in[26];
    const float* h_W2  = (const float*)d_in[27];
    const float* h_b2  = (const float*)d_in[28];

    const int N  = in_sizes[0] / 128;
    const int E1 = in_sizes[3] / 2;
    const int E2 = in_sizes[4] / 2;
    const int nb = (N + 255) / 256;  // 391 for N=100k (scan2 handles <=512)

    // ---- workspace layout ----
    char* p = (char*)d_ws;
    int*   flags  = (int*)p;              p += 64;
    float* fused  = (float*)p;            p += (size_t)N * 96 * 4;
    float* lin    = (float*)p;            p += (size_t)N * 64 * 4;
    float* h1     = (float*)p;            p += (size_t)N * 64 * 4;
    float* hacc   = (float*)p;            p += (size_t)N * 64 * 4;
    float* dinv_a = (float*)p;            p += (size_t)N * 4;
    float* dinv_t = (float*)p;            p += (size_t)N * 4;
    int*   deg_a  = (int*)p;              p += (size_t)N * 4;
    int*   deg_t  = (int*)p;              p += (size_t)N * 4;
    int*   row_a  = (int*)p;              p += (size_t)(N + 1) * 4;
    int*   row_t  = (int*)p;              p += (size_t)(N + 1) * 4;
    int*   cur_a  = (int*)p;              p += (size_t)N * 4;
    int*   cur_t  = (int*)p;              p += (size_t)N * 4;
    int*   bsum   = (int*)p;              p += 512 * 4;
    int2*  edg_a  = (int2*)p;             p += (size_t)E1 * 8;
    int2*  edg_t  = (int2*)p;             p += (size_t)E2 * 8;
    float* out    = (float*)d_out;

    const unsigned rowBlocks = (unsigned)((N + 3) / 4);
    const unsigned nBlocks   = (unsigned)((N + 255) / 256);
    const unsigned e1Blocks  = (unsigned)((E1 + 255) / 256);
    const unsigned e2Blocks  = (unsigned)((E2 + 255) / 256);

    detect_kernel<<<1, 64, 0, stream>>>((const unsigned char*)mask, (const int*)adj_ei, flags);
    hipMemsetAsync(deg_a, 0, (size_t)2 * N * sizeof(int), stream);  // deg_a + deg_t contiguous

    // ---- CSR build: adj graph ----
    degcount_kernel<<<e1Blocks, 256, 0, stream>>>(adj_ei, E1, flags, deg_a);
    dinv_kernel<<<nBlocks, 256, 0, stream>>>(deg_a, dinv_a, N);
    scan1_kernel<<<nb, 256, 0, stream>>>(deg_a, N, bsum);
    scan2_kernel<<<1, 512, 0, stream>>>(bsum, nb);
    scan3_kernel<<<nb, 256, 0, stream>>>(deg_a, N, bsum, row_a, cur_a);
    fill_kernel<<<e1Blocks, 256, 0, stream>>>(adj_ei, E1, flags, dinv_a, cur_a, edg_a);

    // ---- CSR build: transit graph ----
    degcount_kernel<<<e2Blocks, 256, 0, stream>>>(tr_ei, E2, flags, deg_t);
    dinv_kernel<<<nBlocks, 256, 0, stream>>>(deg_t, dinv_t, N);
    scan1_kernel<<<nb, 256, 0, stream>>>(deg_t, N, bsum);
    scan2_kernel<<<1, 512, 0, stream>>>(bsum, nb);
    scan3_kernel<<<nb, 256, 0, stream>>>(deg_t, N, bsum, row_t, cur_t);
    fill_kernel<<<e2Blocks, 256, 0, stream>>>(tr_ei, E2, flags, dinv_t, cur_t, edg_t);

    // ---- encoders -> fused ----
    encoder_kernel<<<rowBlocks, 256, 0, stream>>>(context, target, mask, flags, mask_token,
                                                  ce_W1, ce_b1, ce_g, ce_be, ce_W2, ce_b2,
                                                  te_W, te_b, fused, N);

    // ---- spatial branch ----
    matmul_kernel<96><<<rowBlocks, 256, 0, stream>>>(fused, g1_W, lin, N);
    gather_kernel<<<rowBlocks, 256, 0, stream>>>(row_a, edg_a, dinv_a, lin, g1_b, alpha, 0, h1, N);
    matmul_kernel<64><<<rowBlocks, 256, 0, stream>>>(h1, g2_W, lin, N);
    gather_kernel<<<rowBlocks, 256, 0, stream>>>(row_a, edg_a, dinv_a, lin, g2_b, alpha, 1, hacc, N);

    // ---- transit branch ----
    matmul_kernel<96><<<rowBlocks, 256, 0, stream>>>(fused, t1_W, lin, N);
    gather_kernel<<<rowBlocks, 256, 0, stream>>>(row_t, edg_t, dinv_t, lin, t1_b, alpha, 0, h1, N);
    matmul_kernel<64><<<rowBlocks, 256, 0, stream>>>(h1, t2_W, lin, N);
    gather_kernel<<<rowBlocks, 256, 0, stream>>>(row_t, edg_t, dinv_t, lin, t2_b, alpha, 2, hacc, N);

    // ---- head ----
    head_kernel<<<rowBlocks, 256, 0, stream>>>(hacc, fused, h_W1, h_b1, h_g, h_be,
                                               h_W2, h_b2, out, N);
}

// Round 4
// 942.759 us; speedup vs baseline: 5.2603x; 1.4562x over previous
//
#include <hip/hip_runtime.h>
#include <math.h>

// UrbanModelV2: encoder MLPs -> 4x GCNConv (2 graphs) -> gated combine -> LN-MLP head.
// N=100000, CTX=128, TGT=32, H=64, FUS=96, E1=1.6M, E2=0.8M. All fp32.
//
// R4: dense kernels were L1-bound (1 weight vload per FMA, VALUBusy 34%).
// -> 4 rows per wave: weight loads amortized 4x, row data via wave-uniform
//    scalar loads, wave-private LDS (no barriers).
// -> detect_kernel parallelized (was ~320 serial dependent loads on 1 thread).
// -> gather inner loop unrolled 4x for load-level parallelism.

#define LN_EPS 1e-5f

__device__ __forceinline__ float gelu_exact(float x) {
    return 0.5f * x * (1.0f + erff(x * 0.70710678118654752440f));
}

__device__ __forceinline__ float wave_sum64(float v) {
#pragma unroll
    for (int off = 32; off > 0; off >>= 1)
        v += __shfl_xor(v, off, 64);
    return v;
}

__device__ __forceinline__ int load_edge(const void* ei, int is32, long idx) {
    return is32 ? ((const int*)ei)[idx] : (int)((const long long*)ei)[idx];
}

// ---------------- dtype detection (parallel) ----------------
__global__ __launch_bounds__(256) void detect_kernel(const unsigned char* __restrict__ mask_bytes,
                                                     const int* __restrict__ ei_words,
                                                     int* __restrict__ flags) {
    __shared__ int f0, f1;
    if (threadIdx.x == 0) { f0 = 0; f1 = 0; }
    __syncthreads();
    int i = threadIdx.x;  // 256 threads
    if ((i & 3) != 0 && mask_bytes[i] != 0) f0 = 1;      // nonzero off-word byte => uint8 mask
    if (i < 64 && ei_words[2 * i + 1] != 0) f1 = 1;      // nonzero high word => int32 edges
    __syncthreads();
    if (threadIdx.x == 0) { flags[0] = f0; flags[1] = f1; }
}

// ---------------- CSR build ----------------
__global__ __launch_bounds__(256) void degcount_kernel(const void* __restrict__ ei, int e,
                                                       const int* __restrict__ flags,
                                                       int* __restrict__ deg) {
    int i = blockIdx.x * 256 + threadIdx.x;
    if (i >= e) return;
    int d = load_edge(ei, flags[1], (long)e + i);
    atomicAdd(&deg[d], 1);
}

__global__ __launch_bounds__(256) void dinv_kernel(const int* __restrict__ deg,
                                                   float* __restrict__ dinv, int n) {
    int i = blockIdx.x * 256 + threadIdx.x;
    if (i < n) dinv[i] = rsqrtf((float)deg[i] + 1.0f);  // +1 self-loop
}

__global__ __launch_bounds__(256) void scan1_kernel(const int* __restrict__ deg, int n,
                                                    int* __restrict__ bsum) {
    __shared__ int red[4];
    int i = blockIdx.x * 256 + threadIdx.x;
    int v = (i < n) ? deg[i] : 0;
#pragma unroll
    for (int off = 32; off > 0; off >>= 1)
        v += __shfl_xor(v, off, 64);
    if ((threadIdx.x & 63) == 0) red[threadIdx.x >> 6] = v;
    __syncthreads();
    if (threadIdx.x == 0) bsum[blockIdx.x] = red[0] + red[1] + red[2] + red[3];
}

__global__ __launch_bounds__(512) void scan2_kernel(int* __restrict__ bsum, int nb) {
    __shared__ int s[512];
    int t = threadIdx.x;
    s[t] = (t < nb) ? bsum[t] : 0;
    __syncthreads();
    for (int off = 1; off < 512; off <<= 1) {
        int v = (t >= off) ? s[t - off] : 0;
        __syncthreads();
        if (t >= off) s[t] += v;
        __syncthreads();
    }
    if (t < nb) bsum[t] = (t == 0) ? 0 : s[t - 1];
}

__global__ __launch_bounds__(256) void scan3_kernel(const int* __restrict__ deg, int n,
                                                    const int* __restrict__ boff,
                                                    int* __restrict__ rowptr,
                                                    int* __restrict__ cursor) {
    __shared__ int s[256];
    int t = threadIdx.x;
    int i = blockIdx.x * 256 + t;
    int v = (i < n) ? deg[i] : 0;
    s[t] = v;
    __syncthreads();
    for (int off = 1; off < 256; off <<= 1) {
        int u = (t >= off) ? s[t - off] : 0;
        __syncthreads();
        if (t >= off) s[t] += u;
        __syncthreads();
    }
    int base = boff[blockIdx.x];
    if (i < n) {
        int excl = base + s[t] - v;
        rowptr[i] = excl;
        cursor[i] = excl;
        if (i == n - 1) rowptr[n] = base + s[t];
    }
}

__global__ __launch_bounds__(256) void fill_kernel(const void* __restrict__ ei, int e,
                                                   const int* __restrict__ flags,
                                                   const float* __restrict__ dinv,
                                                   int* __restrict__ cursor,
                                                   int2* __restrict__ edges) {
    int i = blockIdx.x * 256 + threadIdx.x;
    if (i >= e) return;
    int is32 = flags[1];
    int s = load_edge(ei, is32, i);
    int d = load_edge(ei, is32, (long)e + i);
    int pos = atomicAdd(&cursor[d], 1);
    edges[pos] = make_int2(s, __float_as_int(dinv[s]));
}

// ---------------- encoder -> fused [N,96], 4 rows/wave ----------------
__global__ __launch_bounds__(256) void encoder_kernel(
    const float* __restrict__ context, const float* __restrict__ target,
    const void* __restrict__ mask, const int* __restrict__ flags,
    const float* __restrict__ mask_token,
    const float* __restrict__ ce_W1, const float* __restrict__ ce_b1,
    const float* __restrict__ ce_g, const float* __restrict__ ce_beta,
    const float* __restrict__ ce_W2, const float* __restrict__ ce_b2,
    const float* __restrict__ te_W, const float* __restrict__ te_b,
    float* __restrict__ fused, int n)
{
    __shared__ float cbuf[16][64];
    __shared__ float tbuf[16][32];
    int w = threadIdx.x >> 6;
    int j = threadIdx.x & 63;
    int r0 = __builtin_amdgcn_readfirstlane(blockIdx.x * 16 + w * 4);
    if (r0 >= n) return;  // N % 16 == 0: full waves only

    // layer 1: 4 rows, weights loaded once per k
    float y[4];
    float b1 = ce_b1[j];
#pragma unroll
    for (int r = 0; r < 4; ++r) y[r] = b1;
    const float* xr = context + (long)r0 * 128;
#pragma unroll 16
    for (int k = 0; k < 128; ++k) {
        float wv = ce_W1[k * 64 + j];
#pragma unroll
        for (int r = 0; r < 4; ++r)
            y[r] = fmaf(xr[r * 128 + k], wv, y[r]);
    }

    // LayerNorm + GELU per row -> cbuf (wave-private LDS, no barrier)
    float lng = ce_g[j], lnb = ce_beta[j];
#pragma unroll
    for (int r = 0; r < 4; ++r) {
        float mean = wave_sum64(y[r]) * (1.0f / 64.0f);
        float xc = y[r] - mean;
        float var = wave_sum64(xc * xc) * (1.0f / 64.0f);
        cbuf[w * 4 + r][j] = gelu_exact(xc * rsqrtf(var + LN_EPS) * lng + lnb);
    }

    // masked target: 4 rows x 32 dims = 128 elems over 64 lanes
    int tr = j >> 5;   // 0..1
    int tj = j & 31;
#pragma unroll
    for (int rr = 0; rr < 2; ++rr) {
        int r = tr + rr * 2;
        long mi = (long)(r0 + r) * 32 + tj;
        int mraw = flags[0] ? (int)((const unsigned char*)mask)[mi]
                            : ((const int*)mask)[mi];
        float m = mraw ? 1.0f : 0.0f;
        tbuf[w * 4 + r][tj] = target[mi] * (1.0f - m) + mask_token[tj] * m;
    }

    // layer 2: c @ ce_W2 (64->64)
    float y2[4];
    float b2 = ce_b2[j];
#pragma unroll
    for (int r = 0; r < 4; ++r) y2[r] = b2;
#pragma unroll 16
    for (int k = 0; k < 64; ++k) {
        float wv = ce_W2[k * 64 + j];
#pragma unroll
        for (int r = 0; r < 4; ++r)
            y2[r] = fmaf(cbuf[w * 4 + r][k], wv, y2[r]);
    }
#pragma unroll
    for (int r = 0; r < 4; ++r)
        fused[(long)(r0 + r) * 96 + j] = gelu_exact(y2[r]);

    // target encoder (32->32): 4 rows x 32 outs over 64 lanes
#pragma unroll
    for (int rr = 0; rr < 2; ++rr) {
        int r = tr + rr * 2;
        float y3 = te_b[tj];
#pragma unroll
        for (int k = 0; k < 32; ++k)
            y3 = fmaf(tbuf[w * 4 + r][k], te_W[k * 32 + tj], y3);
        fused[(long)(r0 + r) * 96 + 64 + tj] = gelu_exact(y3);
    }
}

// ---------------- dense matmul: y[N,64] = x[N,FIN] @ W[FIN,64], 4 rows/wave ----------------
template <int FIN>
__global__ __launch_bounds__(256) void matmul_kernel(const float* __restrict__ x,
                                                     const float* __restrict__ W,
                                                     float* __restrict__ y, int n) {
    int w = threadIdx.x >> 6;
    int j = threadIdx.x & 63;
    int r0 = __builtin_amdgcn_readfirstlane(blockIdx.x * 16 + w * 4);
    if (r0 >= n) return;
    const float* xr = x + (long)r0 * FIN;
    float acc[4] = {0.0f, 0.0f, 0.0f, 0.0f};
#pragma unroll 16
    for (int k = 0; k < FIN; ++k) {
        float wv = W[k * 64 + j];
#pragma unroll
        for (int r = 0; r < 4; ++r)
            acc[r] = fmaf(xr[r * FIN + k], wv, acc[r]);
    }
#pragma unroll
    for (int r = 0; r < 4; ++r)
        y[(long)(r0 + r) * 64 + j] = acc[r];
}

// ---------------- gather + fused finalize (wave per node, 4x ILP) ----------------
// pre = dinv_d * (sum_{edges} lin[src]*dinv_s + dinv_d*lin[node]) + b
// mode 0: out = gelu(pre); mode 1: out = a*pre; mode 2: out += (1-a)*pre
__global__ __launch_bounds__(256) void gather_kernel(
    const int* __restrict__ rowptr, const int2* __restrict__ edges,
    const float* __restrict__ dinv, const float* __restrict__ lin,
    const float* __restrict__ b, const float* __restrict__ alpha_ptr, int mode,
    float* __restrict__ out, int n)
{
    int w = threadIdx.x >> 6;
    int j = threadIdx.x & 63;
    int node = __builtin_amdgcn_readfirstlane(blockIdx.x * 4 + w);
    if (node >= n) return;

    int beg = rowptr[node];
    int end = rowptr[node + 1];
    float acc = 0.0f;
    for (int base = beg; base < end; base += 64) {
        int cnt = end - base;
        if (cnt > 64) cnt = 64;
        int2 rec = (j < cnt) ? edges[base + j] : make_int2(0, 0);
        int sj = rec.x;
        float dsj = __int_as_float(rec.y);
        int t = 0;
        for (; t + 4 <= cnt; t += 4) {
            int s0 = __shfl(sj, t, 64),     s1 = __shfl(sj, t + 1, 64);
            int s2 = __shfl(sj, t + 2, 64), s3 = __shfl(sj, t + 3, 64);
            float d0 = __shfl(dsj, t, 64),     d1 = __shfl(dsj, t + 1, 64);
            float d2 = __shfl(dsj, t + 2, 64), d3 = __shfl(dsj, t + 3, 64);
            float v0 = lin[(long)s0 * 64 + j];
            float v1 = lin[(long)s1 * 64 + j];
            float v2 = lin[(long)s2 * 64 + j];
            float v3 = lin[(long)s3 * 64 + j];
            acc = fmaf(v0, d0, acc);
            acc = fmaf(v1, d1, acc);
            acc = fmaf(v2, d2, acc);
            acc = fmaf(v3, d3, acc);
        }
        for (; t < cnt; ++t) {
            int s = __shfl(sj, t, 64);
            float ds = __shfl(dsj, t, 64);
            acc = fmaf(lin[(long)s * 64 + j], ds, acc);
        }
    }
    float dd = dinv[node];
    float pre = dd * (acc + dd * lin[(long)node * 64 + j]) + b[j];

    long oi = (long)node * 64 + j;
    if (mode == 0) {
        out[oi] = gelu_exact(pre);
    } else {
        float a = 1.0f / (1.0f + expf(-alpha_ptr[0]));
        if (mode == 1) out[oi] = a * pre;
        else           out[oi] += (1.0f - a) * pre;
    }
}

// ---------------- head, 4 rows/wave ----------------
__global__ __launch_bounds__(256) void head_kernel(
    const float* __restrict__ hacc, const float* __restrict__ fused,
    const float* __restrict__ h_W1, const float* __restrict__ h_b1,
    const float* __restrict__ h_g, const float* __restrict__ h_beta,
    const float* __restrict__ h_W2, const float* __restrict__ h_b2,
    float* __restrict__ out, int n)
{
    __shared__ float zbuf[16][160];
    __shared__ float z2[16][64];
    int w = threadIdx.x >> 6;
    int j = threadIdx.x & 63;
    int r0 = __builtin_amdgcn_readfirstlane(blockIdx.x * 16 + w * 4);
    if (r0 >= n) return;

#pragma unroll
    for (int r = 0; r < 4; ++r) {
        zbuf[w * 4 + r][j] = hacc[(long)(r0 + r) * 64 + j];
        zbuf[w * 4 + r][64 + j] = fused[(long)(r0 + r) * 96 + j];
        if (j < 32) zbuf[w * 4 + r][128 + j] = fused[(long)(r0 + r) * 96 + 64 + j];
    }

    float y[4];
    float b1 = h_b1[j];
#pragma unroll
    for (int r = 0; r < 4; ++r) y[r] = b1;
#pragma unroll 16
    for (int k = 0; k < 160; ++k) {
        float wv = h_W1[k * 64 + j];
#pragma unroll
        for (int r = 0; r < 4; ++r)
            y[r] = fmaf(zbuf[w * 4 + r][k], wv, y[r]);
    }

    float lng = h_g[j], lnb = h_beta[j];
#pragma unroll
    for (int r = 0; r < 4; ++r) {
        float mean = wave_sum64(y[r]) * (1.0f / 64.0f);
        float xc = y[r] - mean;
        float var = wave_sum64(xc * xc) * (1.0f / 64.0f);
        z2[w * 4 + r][j] = gelu_exact(xc * rsqrtf(var + LN_EPS) * lng + lnb);
    }

    int tr = j >> 5;
    int tj = j & 31;
#pragma unroll
    for (int rr = 0; rr < 2; ++rr) {
        int r = tr + rr * 2;
        float o = h_b2[tj];
#pragma unroll
        for (int k = 0; k < 64; ++k)
            o = fmaf(z2[w * 4 + r][k], h_W2[k * 32 + tj], o);
        out[(long)(r0 + r) * 32 + tj] = o;
    }
}

extern "C" void kernel_launch(void* const* d_in, const int* in_sizes, int n_in,
                              void* d_out, int out_size, void* d_ws, size_t ws_size,
                              hipStream_t stream) {
    const float* context    = (const float*)d_in[0];
    const float* target     = (const float*)d_in[1];
    const void*  mask       = d_in[2];
    const void*  adj_ei     = d_in[3];
    const void*  tr_ei      = d_in[4];
    const float* mask_token = (const float*)d_in[5];
    const float* ce_W1 = (const float*)d_in[6];
    const float* ce_b1 = (const float*)d_in[7];
    const float* ce_g  = (const float*)d_in[8];
    const float* ce_be = (const float*)d_in[9];
    const float* ce_W2 = (const float*)d_in[10];
    const float* ce_b2 = (const float*)d_in[11];
    const float* te_W  = (const float*)d_in[12];
    const float* te_b  = (const float*)d_in[13];
    const float* g1_W  = (const float*)d_in[14];
    const float* g1_b  = (const float*)d_in[15];
    const float* g2_W  = (const float*)d_in[16];
    const float* g2_b  = (const float*)d_in[17];
    const float* t1_W  = (const float*)d_in[18];
    const float* t1_b  = (const float*)d_in[19];
    const float* t2_W  = (const float*)d_in[20];
    const float* t2_b  = (const float*)d_in[21];
    const float* alpha = (const float*)d_in[22];
    const float* h_W1  = (const float*)d_in[23];
    const float* h_b1  = (const float*)d_in[24];
    const float* h_g   = (const float*)d_in[25];
    const float* h_be  = (const float*)d_in[26];
    const float* h_W2  = (const float*)d_in[27];
    const float* h_b2  = (const float*)d_in[28];

    const int N  = in_sizes[0] / 128;
    const int E1 = in_sizes[3] / 2;
    const int E2 = in_sizes[4] / 2;
    const int nb = (N + 255) / 256;  // 391 (scan2 handles <=512)

    // ---- workspace layout ----
    char* p = (char*)d_ws;
    int*   flags  = (int*)p;              p += 64;
    float* fused  = (float*)p;            p += (size_t)N * 96 * 4;
    float* lin    = (float*)p;            p += (size_t)N * 64 * 4;
    float* h1     = (float*)p;            p += (size_t)N * 64 * 4;
    float* hacc   = (float*)p;            p += (size_t)N * 64 * 4;
    float* dinv_a = (float*)p;            p += (size_t)N * 4;
    float* dinv_t = (float*)p;            p += (size_t)N * 4;
    int*   deg_a  = (int*)p;              p += (size_t)N * 4;
    int*   deg_t  = (int*)p;              p += (size_t)N * 4;
    int*   row_a  = (int*)p;              p += (size_t)(N + 1) * 4;
    int*   row_t  = (int*)p;              p += (size_t)(N + 1) * 4;
    int*   cur_a  = (int*)p;              p += (size_t)N * 4;
    int*   cur_t  = (int*)p;              p += (size_t)N * 4;
    int*   bsum   = (int*)p;              p += 512 * 4;
    int2*  edg_a  = (int2*)p;             p += (size_t)E1 * 8;
    int2*  edg_t  = (int2*)p;             p += (size_t)E2 * 8;
    float* out    = (float*)d_out;

    const unsigned rowBlocks16 = (unsigned)((N + 15) / 16);
    const unsigned nodeBlocks  = (unsigned)((N + 3) / 4);
    const unsigned nBlocks     = (unsigned)((N + 255) / 256);
    const unsigned e1Blocks    = (unsigned)((E1 + 255) / 256);
    const unsigned e2Blocks    = (unsigned)((E2 + 255) / 256);

    detect_kernel<<<1, 256, 0, stream>>>((const unsigned char*)mask, (const int*)adj_ei, flags);
    hipMemsetAsync(deg_a, 0, (size_t)2 * N * sizeof(int), stream);  // deg_a+deg_t contiguous

    // ---- CSR build: adj ----
    degcount_kernel<<<e1Blocks, 256, 0, stream>>>(adj_ei, E1, flags, deg_a);
    dinv_kernel<<<nBlocks, 256, 0, stream>>>(deg_a, dinv_a, N);
    scan1_kernel<<<nb, 256, 0, stream>>>(deg_a, N, bsum);
    scan2_kernel<<<1, 512, 0, stream>>>(bsum, nb);
    scan3_kernel<<<nb, 256, 0, stream>>>(deg_a, N, bsum, row_a, cur_a);
    fill_kernel<<<e1Blocks, 256, 0, stream>>>(adj_ei, E1, flags, dinv_a, cur_a, edg_a);

    // ---- CSR build: transit ----
    degcount_kernel<<<e2Blocks, 256, 0, stream>>>(tr_ei, E2, flags, deg_t);
    dinv_kernel<<<nBlocks, 256, 0, stream>>>(deg_t, dinv_t, N);
    scan1_kernel<<<nb, 256, 0, stream>>>(deg_t, N, bsum);
    scan2_kernel<<<1, 512, 0, stream>>>(bsum, nb);
    scan3_kernel<<<nb, 256, 0, stream>>>(deg_t, N, bsum, row_t, cur_t);
    fill_kernel<<<e2Blocks, 256, 0, stream>>>(tr_ei, E2, flags, dinv_t, cur_t, edg_t);

    // ---- encoders -> fused ----
    encoder_kernel<<<rowBlocks16, 256, 0, stream>>>(context, target, mask, flags, mask_token,
                                                    ce_W1, ce_b1, ce_g, ce_be, ce_W2, ce_b2,
                                                    te_W, te_b, fused, N);

    // ---- spatial branch ----
    matmul_kernel<96><<<rowBlocks16, 256, 0, stream>>>(fused, g1_W, lin, N);
    gather_kernel<<<nodeBlocks, 256, 0, stream>>>(row_a, edg_a, dinv_a, lin, g1_b, alpha, 0, h1, N);
    matmul_kernel<64><<<rowBlocks16, 256, 0, stream>>>(h1, g2_W, lin, N);
    gather_kernel<<<nodeBlocks, 256, 0, stream>>>(row_a, edg_a, dinv_a, lin, g2_b, alpha, 1, hacc, N);

    // ---- transit branch ----
    matmul_kernel<96><<<rowBlocks16, 256, 0, stream>>>(fused, t1_W, lin, N);
    gather_kernel<<<nodeBlocks, 256, 0, stream>>>(row_t, edg_t, dinv_t, lin, t1_b, alpha, 0, h1, N);
    matmul_kernel<64><<<rowBlocks16, 256, 0, stream>>>(h1, t2_W, lin, N);
    gather_kernel<<<nodeBlocks, 256, 0, stream>>>(row_t, edg_t, dinv_t, lin, t2_b, alpha, 2, hacc, N);

    // ---- head ----
    head_kernel<<<rowBlocks16, 256, 0, stream>>>(hacc, fused, h_W1, h_b1, h_g, h_be,
                                                 h_W2, h_b2, out, N);
}